// Round 9
// baseline (480.664 us; speedup 1.0000x reference)
//
#include <hip/hip_runtime.h>

// B=512, V=256, W=64, H=64. Outputs: x_tilde_seq (64,512,256) fp32, h_seq (64,512,64) fp32.
// One block = TWO batches, 1024 threads (16 waves = 4/SIMD), 256 blocks, 1 block/CU.
// 4 waves/SIMD (vs 2 in R6/R8) to fill barrier/latency stalls. Register cap 128/thread:
// persistent ~75 regs = w_ih fp16 quarter-row (32 h2) + w_hh fp16 (8) + w_w (8) + misc.

#define KLOG2E  1.4426950408889634f   // log2(e)
#define K2LOG2E 2.8853900817779268f   // 2*log2(e)

typedef _Float16 h2 __attribute__((ext_vector_type(2)));
union H2U { h2 h; unsigned u; };

__device__ __forceinline__ float frcp(float x)  { return __builtin_amdgcn_rcpf(x); }
__device__ __forceinline__ float fexp2(float x) { return __builtin_amdgcn_exp2f(x); }
__device__ __forceinline__ float fsigmoid(float x) { return frcp(1.f + fexp2(-KLOG2E * x)); }
__device__ __forceinline__ float ftanh(float x) { return 1.f - 2.f * frcp(fexp2(K2LOG2E * x) + 1.f); }

#if __has_builtin(__builtin_amdgcn_fdot2)
__device__ __forceinline__ float fdot2(h2 a, h2 b, float c) { return __builtin_amdgcn_fdot2(a, b, c, false); }
#else
__device__ __forceinline__ float fdot2(h2 a, h2 b, float c) { return c + (float)a.x*(float)b.x + (float)a.y*(float)b.y; }
#endif

__device__ __forceinline__ unsigned pkrtz_u(float a, float b) {
#if __has_builtin(__builtin_amdgcn_cvt_pkrtz)
    H2U r; r.h = __builtin_bit_cast(h2, __builtin_amdgcn_cvt_pkrtz(a, b)); return r.u;
#else
    H2U r; r.h.x = (_Float16)a; r.h.y = (_Float16)b; return r.u;
#endif
}
__device__ __forceinline__ h2 pk_rtn(float a, float b) {   // round-to-nearest (weights)
    h2 r; r.x = (_Float16)a; r.y = (_Float16)b; return r;
}

// LDS layout (float slots)
#define L_EA   0                    // E_A [256][68] fp32
#define L_EB   17408                // E_B [256][68]
#define L_PSA  34816                // gate partials A [1024] (4 quarter-slices x 256)
#define L_PSB  35840                // [1024]
#define L_EXFA 36864                // e*x fp32 A [256]
#define L_EXFB 37120
#define L_XHA  37376                // e*x packed h2 A [128 u32]
#define L_XHB  37504
#define L_EWA  37632                // e_w A [64]
#define L_EWB  37696
#define L_HCA  37760                // h||c fp32 A [128]
#define L_HCB  37888
#define L_HHA  38016                // h packed h2 A [32 u32]
#define L_HHB  38048
#define L_BI   38080                // bias b_ih+b_hh [256]
#define L_WV   38336                // -2*w_v [64]
#define L_WS   38400                // wave e-sums [16]: 0-7 = A, 8-15 = B
#define L_TOT  38416                // 153664 bytes <= 160K (1 block/CU)

__global__ __launch_bounds__(1024, 1) void enc_kernel(
    const float* __restrict__ x,     // (512,256,64)
    const float* __restrict__ w_ih,  // (256,256)
    const float* __restrict__ w_hh,  // (256,64)
    const float* __restrict__ b_ih,  // (256)
    const float* __restrict__ b_hh,  // (256)
    const float* __restrict__ w_v,   // (64)
    const float* __restrict__ w_w,   // (64,128)
    const float* __restrict__ b_w,   // (64)
    const float* __restrict__ w_u,   // (64,64)
    const float* __restrict__ b_u,   // (64)
    float* __restrict__ out_xt,      // (64,512,256)
    float* __restrict__ out_h)       // (64,512,64)
{
    extern __shared__ float lds[];
    float*    EA   = lds + L_EA;    float*    EB   = lds + L_EB;
    float*    psA  = lds + L_PSA;   float*    psB  = lds + L_PSB;
    float*    exfA = lds + L_EXFA;  float*    exfB = lds + L_EXFB;
    unsigned* xhA  = (unsigned*)(lds + L_XHA);
    unsigned* xhB  = (unsigned*)(lds + L_XHB);
    float*    ewA  = lds + L_EWA;   float*    ewB  = lds + L_EWB;
    float*    hcA  = lds + L_HCA;   float*    hcB  = lds + L_HCB;
    unsigned* hhA  = (unsigned*)(lds + L_HHA);
    unsigned* hhB  = (unsigned*)(lds + L_HHB);
    float*    biasL= lds + L_BI;
    float*    wv2L = lds + L_WV;
    float*    wsum = lds + L_WS;

    const int tid  = threadIdx.x;       // 0..1023
    const int lane = tid & 63;
    const int wvi  = tid >> 6;          // wave 0..15
    const int bA   = blockIdx.x;
    const int bB   = blockIdx.x + 256;

    // P4 identity: gate row j4, v-quarter sgq
    const int j4  = tid & 255;
    const int sgq = tid >> 8;           // 0..3: v-slice [sgq*64,+64), k-slice [sgq*16,+16)
    // P1 identity: batch p1b, output w8, k-group kg (k = kg*8..+8)
    const int p1b = tid >> 9;
    const int w8  = (tid >> 3) & 63;
    const int kg  = tid & 7;
    // P2 identity: batch p2b, v index v2, w-half half2
    const int p2b   = wvi >> 3;
    const int v2    = ((wvi & 7) << 5) + (lane & 31);
    const int half2 = lane >> 5;

    // ---- one-time LDS fills ----
    if (tid < 256) biasL[tid] = b_ih[tid] + b_hh[tid];
    if (tid < 64)  wv2L[tid] = -2.f * w_v[tid];
    if (tid < 128) { hcA[tid] = 0.f; hcB[tid] = 0.f; }
    if (tid < 32)  { hhA[tid] = 0u; hhB[tid] = 0u; }

    float Sv = 0.f;
#pragma unroll
    for (int wi = 0; wi < 64; ++wi) Sv += w_v[wi];   // uniform scalar loads
    const float bu_lane = b_u[lane];

    // ---- E init: 16 waves x 16 rows per batch; E[v][w]=exp(2*(x[b,v,:]@w_u[w,:]+b_u[w])) ----
#pragma unroll 1
    for (int bb = 0; bb < 2; ++bb) {
        float* E = bb ? EB : EA;
        const int b = bb ? bB : bA;
#pragma unroll 1
        for (int half = 0; half < 2; ++half) {
            float4 wu_r[8];
#pragma unroll
            for (int i = 0; i < 8; ++i)
                wu_r[i] = *(const float4*)&w_u[lane*64 + half*32 + 4*i];
            const float* xb = x + b*16384 + half*32;
#pragma unroll 2
            for (int vi = 0; vi < 16; ++vi) {
                int v = __builtin_amdgcn_readfirstlane(wvi*16 + vi);
                const float4* xr = (const float4*)(xb + v*64);
                float acc = 0.f;
#pragma unroll
                for (int i = 0; i < 8; ++i) {
                    float4 xx = xr[i]; float4 wu = wu_r[i];
                    acc += xx.x*wu.x + xx.y*wu.y + xx.z*wu.z + xx.w*wu.w;
                }
                if (half == 0) E[v*68 + lane] = acc + bu_lane;
                else           E[v*68 + lane] = fexp2(K2LOG2E * (E[v*68 + lane] + acc));
            }
        }
    }
    __syncthreads();

    // ---- persistent per-thread weights (after init; ~48 regs) ----
    h2 wihr2[32];   // w_ih row j4, v-quarter [sgq*64,+64) fp16
    {
        const float4* g4 = (const float4*)(w_ih + j4*256 + sgq*64);
#pragma unroll
        for (int i = 0; i < 16; ++i) {
            float4 v4 = g4[i];
            wihr2[2*i]     = pk_rtn(v4.x, v4.y);
            wihr2[2*i + 1] = pk_rtn(v4.z, v4.w);
        }
    }
    h2 whh2[8];     // w_hh row j4, k-quarter [sgq*16,+16) fp16
    {
        const float4* h4 = (const float4*)(w_hh + j4*64 + sgq*16);
#pragma unroll
        for (int i = 0; i < 4; ++i) {
            float4 v4 = h4[i];
            whh2[2*i]     = pk_rtn(v4.x, v4.y);
            whh2[2*i + 1] = pk_rtn(v4.z, v4.w);
        }
    }
    float4 www0 = *(const float4*)&w_w[w8*128 + kg*8];
    float4 www1 = *(const float4*)&w_w[w8*128 + kg*8 + 4];
    const float bwr = b_w[w8];

    const float* xrow = x + (p2b ? bB : bA)*16384 + v2*64;
    float xcur = (half2 == 0) ? xrow[0] : 0.f;

    for (int t = 0; t < 64; ++t) {
        // ---- P1: wout -> ew. thread (p1b, w8, kg); hc reads 2-addr/bank (free) ----
        {
            const float* hcx = p1b ? hcB : hcA;
            float4 h0 = *(const float4*)&hcx[kg*8];
            float4 h1 = *(const float4*)&hcx[kg*8 + 4];
            float acc = h0.x*www0.x + h0.y*www0.y + h0.z*www0.z + h0.w*www0.w
                      + h1.x*www1.x + h1.y*www1.y + h1.z*www1.z + h1.w*www1.w;
            acc += __shfl_xor(acc, 1, 64);
            acc += __shfl_xor(acc, 2, 64);
            acc += __shfl_xor(acc, 4, 64);
            if (kg == 0) (p1b ? ewB : ewA)[w8] = fexp2(K2LOG2E * (acc + bwr));
        }
        float xnxt = (half2 == 0 && t < 63) ? xrow[t + 1] : 0.f;  // prefetch across B1
        __syncthreads();   // B1

        // ---- P2: score half-row per thread; halves combined by shfl_xor(32) ----
        {
            const float* Erow = (p2b ? EB : EA) + v2*68 + half2*32;
            const float* ewX  = (p2b ? ewB : ewA) + half2*32;
            const float* wvX  = wv2L + half2*32;
            float a0 = 0.f, a1 = 0.f;
#pragma unroll
            for (int q = 0; q < 4; ++q) {
                float4 e4 = *(const float4*)&Erow[4*q];
                float4 c4 = *(const float4*)&ewX[4*q];   // broadcast
                float4 v4 = *(const float4*)&wvX[4*q];   // broadcast
                a0 += v4.x * frcp(e4.x*c4.x + 1.f);
                a0 += v4.y * frcp(e4.y*c4.y + 1.f);
                a0 += v4.z * frcp(e4.z*c4.z + 1.f);
                a0 += v4.w * frcp(e4.w*c4.w + 1.f);
            }
#pragma unroll
            for (int q = 4; q < 8; ++q) {
                float4 e4 = *(const float4*)&Erow[4*q];
                float4 c4 = *(const float4*)&ewX[4*q];
                float4 v4 = *(const float4*)&wvX[4*q];
                a1 += v4.x * frcp(e4.x*c4.x + 1.f);
                a1 += v4.y * frcp(e4.y*c4.y + 1.f);
                a1 += v4.z * frcp(e4.z*c4.z + 1.f);
                a1 += v4.w * frcp(e4.w*c4.w + 1.f);
            }
            float acc = a0 + a1 + (half2 ? 0.f : Sv);
            acc += __shfl_xor(acc, 32, 64);              // combine w-halves
            float e  = fexp2(KLOG2E * acc);  // |score| <= sum|w_v| ~2.6: no max-subtract
            float ex = e * xcur;
            float s = e;                                  // wave e-sum (lanes 0-31 valid)
            s += __shfl_xor(s, 1, 64);  s += __shfl_xor(s, 2, 64);
            s += __shfl_xor(s, 4, 64);  s += __shfl_xor(s, 8, 64);
            s += __shfl_xor(s, 16, 64);
            if (lane == 0) wsum[wvi] = s;
            if (half2 == 0) {
                (p2b ? exfB : exfA)[v2] = ex;
                float ex2 = __shfl_xor(ex, 1, 64);
                if (!(lane & 1)) (p2b ? xhB : xhA)[v2 >> 1] = pkrtz_u(ex, ex2);
            }
        }
        xcur = xnxt;
        __syncthreads();   // B2

        // ---- P4: gates partials (both batches) + out_xt stores ----
        {
            float rA = ((wsum[0] + wsum[1]) + (wsum[2] + wsum[3]))
                     + ((wsum[4] + wsum[5]) + (wsum[6] + wsum[7]));
            float rB = ((wsum[8] + wsum[9]) + (wsum[10] + wsum[11]))
                     + ((wsum[12] + wsum[13]) + (wsum[14] + wsum[15]));
            rA = frcp(rA); rB = frcp(rB);
            if (sgq == 0)      out_xt[t*131072 + bA*256 + j4] = rA * exfA[j4];
            else if (sgq == 1) out_xt[t*131072 + bB*256 + j4] = rB * exfB[j4];

            float aA = 0.f, aB = 0.f;
            const uint4* xxA = (const uint4*)xhA + sgq*8;   // wave-uniform broadcast
            const uint4* xxB = (const uint4*)xhB + sgq*8;
#pragma unroll
            for (int i = 0; i < 8; ++i) {
                uint4 ua = xxA[i], ub = xxB[i];
                H2U a0, a1, a2, a3, b0, b1, b2, b3;
                a0.u = ua.x; a1.u = ua.y; a2.u = ua.z; a3.u = ua.w;
                b0.u = ub.x; b1.u = ub.y; b2.u = ub.z; b3.u = ub.w;
                aA = fdot2(a0.h, wihr2[4*i + 0], aA);
                aA = fdot2(a1.h, wihr2[4*i + 1], aA);
                aA = fdot2(a2.h, wihr2[4*i + 2], aA);
                aA = fdot2(a3.h, wihr2[4*i + 3], aA);
                aB = fdot2(b0.h, wihr2[4*i + 0], aB);
                aB = fdot2(b1.h, wihr2[4*i + 1], aB);
                aB = fdot2(b2.h, wihr2[4*i + 2], aB);
                aB = fdot2(b3.h, wihr2[4*i + 3], aB);
            }
            float ahA = 0.f, ahB = 0.f;
            const uint4* hha = (const uint4*)hhA + sgq*2;   // broadcast
            const uint4* hhb = (const uint4*)hhB + sgq*2;
#pragma unroll
            for (int i = 0; i < 2; ++i) {
                uint4 ua = hha[i], ub = hhb[i];
                H2U a0, a1, a2, a3, b0, b1, b2, b3;
                a0.u = ua.x; a1.u = ua.y; a2.u = ua.z; a3.u = ua.w;
                b0.u = ub.x; b1.u = ub.y; b2.u = ub.z; b3.u = ub.w;
                ahA = fdot2(a0.h, whh2[4*i + 0], ahA);
                ahA = fdot2(a1.h, whh2[4*i + 1], ahA);
                ahA = fdot2(a2.h, whh2[4*i + 2], ahA);
                ahA = fdot2(a3.h, whh2[4*i + 3], ahA);
                ahB = fdot2(b0.h, whh2[4*i + 0], ahB);
                ahB = fdot2(b1.h, whh2[4*i + 1], ahB);
                ahB = fdot2(b2.h, whh2[4*i + 2], ahB);
                ahB = fdot2(b3.h, whh2[4*i + 3], ahB);
            }
            psA[sgq*256 + j4] = rA*aA + ahA;
            psB[sgq*256 + j4] = rB*aB + ahB;
        }
        __syncthreads();   // B4

        // ---- P5: LSTM cell (wave0 = A, wave1 = B) ----
        if (wvi < 2) {
            float*    ps = wvi ? psB : psA;
            float*    hc = wvi ? hcB : hcA;
            unsigned* hh = wvi ? hhB : hhA;
            float*    oh = out_h + t*32768 + (wvi ? bB : bA)*64;
            const int k = lane;
            float gi = biasL[k      ] + (ps[k      ] + ps[256 + k      ]) + (ps[512 + k      ] + ps[768 + k      ]);
            float gf = biasL[64  + k] + (ps[64  + k] + ps[320 + k      ]) + (ps[576 + k      ] + ps[832 + k      ]);
            float gg = biasL[128 + k] + (ps[128 + k] + ps[384 + k      ]) + (ps[640 + k      ] + ps[896 + k      ]);
            float go = biasL[192 + k] + (ps[192 + k] + ps[448 + k      ]) + (ps[704 + k      ] + ps[960 + k      ]);
            gi = fsigmoid(gi); gf = fsigmoid(gf);
            gg = ftanh(gg);    go = fsigmoid(go);
            float cn = gf * hc[64 + k] + gi * gg;
            float hn = go * ftanh(cn);
            hc[k] = hn; hc[64 + k] = cn;
            float hp = __shfl_xor(hn, 1, 64);
            if (!(lane & 1)) hh[k >> 1] = pkrtz_u(hn, hp);
            oh[k] = hn;
        }
        __syncthreads();   // B5
    }
}

extern "C" void kernel_launch(void* const* d_in, const int* in_sizes, int n_in,
                              void* d_out, int out_size, void* d_ws, size_t ws_size,
                              hipStream_t stream) {
    const float* x    = (const float*)d_in[0];
    const float* w_ih = (const float*)d_in[1];
    const float* w_hh = (const float*)d_in[2];
    const float* b_ih = (const float*)d_in[3];
    const float* b_hh = (const float*)d_in[4];
    const float* w_v  = (const float*)d_in[5];
    const float* w_w  = (const float*)d_in[6];
    const float* b_w  = (const float*)d_in[7];
    const float* w_u  = (const float*)d_in[8];
    const float* b_u  = (const float*)d_in[9];

    float* out_xt = (float*)d_out;
    float* out_h  = out_xt + 64*512*256;

    const size_t shbytes = (size_t)L_TOT * sizeof(float);  // 153664 B
    (void)hipFuncSetAttribute((const void*)enc_kernel,
                        hipFuncAttributeMaxDynamicSharedMemorySize, (int)shbytes);
    enc_kernel<<<dim3(256), dim3(1024), shbytes, stream>>>(
        x, w_ih, w_hh, b_ih, b_hh, w_v, w_w, b_w, w_u, b_u, out_xt, out_h);
}

// Round 10
// 314.114 us; speedup vs baseline: 1.5302x; 1.5302x over previous
//
#include <hip/hip_runtime.h>

// B=512, V=256, W=64, H=64. Outputs: x_tilde_seq (64,512,256) fp32, h_seq (64,512,64) fp32.
// One block = TWO batches (bA, bA+256) interleaved; 256 blocks x 512 thr, 1 block/CU, 8 waves.
// R6 structure (306us) + deferred softmax (4 barriers/step) + dependency-chain surgery:
//   P2: 4 independent accumulators (was 1 x 64-deep chain)
//   P4: 8 x-part fdot2 chains (jj-structure) + separate h-part accs; r-scale folded at write
//   P5: explicit tree sums
// Persistent ~120 regs: w_ih fp16 (64), w_hh fp32 (32), w_w fp32 (16) -- proven no-spill at 256 budget.

#define KLOG2E  1.4426950408889634f   // log2(e)
#define K2LOG2E 2.8853900817779268f   // 2*log2(e)

typedef _Float16 h2 __attribute__((ext_vector_type(2)));
union H2U { h2 h; unsigned u; };

__device__ __forceinline__ float frcp(float x)  { return __builtin_amdgcn_rcpf(x); }
__device__ __forceinline__ float fexp2(float x) { return __builtin_amdgcn_exp2f(x); }
__device__ __forceinline__ float fsigmoid(float x) { return frcp(1.f + fexp2(-KLOG2E * x)); }
__device__ __forceinline__ float ftanh(float x) { return 1.f - 2.f * frcp(fexp2(K2LOG2E * x) + 1.f); }

#if __has_builtin(__builtin_amdgcn_fdot2)
__device__ __forceinline__ float fdot2(h2 a, h2 b, float c) { return __builtin_amdgcn_fdot2(a, b, c, false); }
#else
__device__ __forceinline__ float fdot2(h2 a, h2 b, float c) { return c + (float)a.x*(float)b.x + (float)a.y*(float)b.y; }
#endif

__device__ __forceinline__ unsigned pkrtz_u(float a, float b) {
#if __has_builtin(__builtin_amdgcn_cvt_pkrtz)
    H2U r; r.h = __builtin_bit_cast(h2, __builtin_amdgcn_cvt_pkrtz(a, b)); return r.u;
#else
    H2U r; r.h.x = (_Float16)a; r.h.y = (_Float16)b; return r.u;
#endif
}
__device__ __forceinline__ h2 pk_rtn(float a, float b) {   // round-to-nearest (weights)
    h2 r; r.x = (_Float16)a; r.y = (_Float16)b; return r;
}

// LDS layout (float slots)
#define L_EA   0                    // E_A [256][68] fp32
#define L_EB   17408                // E_B [256][68]
#define L_PSA  34816                // gate partials A [2048] (8 slices x 256)
#define L_PSB  36864                // [2048]
#define L_EXFA 38912                // e*x fp32 A [256]
#define L_EXFB 39168
#define L_XHA  39424                // e*x packed h2 A [128 u32]
#define L_XHB  39552
#define L_EWA  39680                // e_w A [64]
#define L_EWB  39744
#define L_HCA  39808                // h||c fp32 A [128]
#define L_HCB  39936
#define L_BI   40064                // bias b_ih+b_hh [256]
#define L_WV   40320                // -2*w_v [64]
#define L_WS   40384                // wave e-sums [8]: 0-3 = A, 4-7 = B
#define L_TOT  40392                // 161568 bytes <= 160K LDS (1 block/CU)

__global__ __launch_bounds__(512, 2) void enc_kernel(
    const float* __restrict__ x,     // (512,256,64)
    const float* __restrict__ w_ih,  // (256,256)
    const float* __restrict__ w_hh,  // (256,64)
    const float* __restrict__ b_ih,  // (256)
    const float* __restrict__ b_hh,  // (256)
    const float* __restrict__ w_v,   // (64)
    const float* __restrict__ w_w,   // (64,128)
    const float* __restrict__ b_w,   // (64)
    const float* __restrict__ w_u,   // (64,64)
    const float* __restrict__ b_u,   // (64)
    float* __restrict__ out_xt,      // (64,512,256)
    float* __restrict__ out_h)       // (64,512,64)
{
    extern __shared__ float lds[];
    float*    EA   = lds + L_EA;    float*    EB   = lds + L_EB;
    float*    psA  = lds + L_PSA;   float*    psB  = lds + L_PSB;
    float*    exfA = lds + L_EXFA;  float*    exfB = lds + L_EXFB;
    unsigned* xhA  = (unsigned*)(lds + L_XHA);
    unsigned* xhB  = (unsigned*)(lds + L_XHB);
    float*    ewA  = lds + L_EWA;   float*    ewB  = lds + L_EWB;
    float*    hcA  = lds + L_HCA;   float*    hcB  = lds + L_HCB;
    float*    biasL= lds + L_BI;
    float*    wv2L = lds + L_WV;
    float*    wsum = lds + L_WS;

    const int tid  = threadIdx.x;
    const int lane = tid & 63;
    const int wvi  = tid >> 6;            // wave 0..7
    const int bA   = blockIdx.x;
    const int bB   = blockIdx.x + 256;

    // ---- persistent per-thread weights ----
    // gates: thread (jg=lane, sg=wvi) -> rows jg+64*jj over v-slice [32*sg,+32), fp16-packed
    h2    wihr2[64];
    float whhr[32];
    {
        const int jg = lane, sg = wvi;
#pragma unroll
        for (int jj = 0; jj < 4; ++jj) {
            const float4* g4 = (const float4*)(w_ih + (jg + 64*jj)*256 + sg*32);
#pragma unroll
            for (int i = 0; i < 8; ++i) {
                float4 v4 = g4[i];
                wihr2[jj*16 + 2*i + 0] = pk_rtn(v4.x, v4.y);
                wihr2[jj*16 + 2*i + 1] = pk_rtn(v4.z, v4.w);
            }
            const float4* h4 = (const float4*)(w_hh + (jg + 64*jj)*64 + sg*8);
            float4 u0 = h4[0], u1 = h4[1];
            whhr[jj*8 + 0] = u0.x; whhr[jj*8 + 1] = u0.y;
            whhr[jj*8 + 2] = u0.z; whhr[jj*8 + 3] = u0.w;
            whhr[jj*8 + 4] = u1.x; whhr[jj*8 + 5] = u1.y;
            whhr[jj*8 + 6] = u1.z; whhr[jj*8 + 7] = u1.w;
        }
    }
    // wout: thread (w8 = wvi*8+(lane&7), kg = lane>>3) covers k = kg*4 + 32m (m=0..3)
    const int w8 = wvi*8 + (lane & 7);
    const int kg = lane >> 3;
    float4 www4[4];
#pragma unroll
    for (int m = 0; m < 4; ++m)
        www4[m] = *(const float4*)&w_w[w8*128 + kg*4 + 32*m];
    const float bwr = b_w[w8];
    float Sv = 0.f;
#pragma unroll
    for (int wi = 0; wi < 64; ++wi) Sv += w_v[wi];   // uniform scalar loads
    const float bu_lane = b_u[lane];

    // ---- one-time LDS fills ----
    if (tid < 256) biasL[tid] = b_ih[tid] + b_hh[tid];
    if (tid < 64) wv2L[tid] = -2.f * w_v[tid];
    if (tid < 128) { hcA[tid] = 0.f; hcB[tid] = 0.f; }

    // ---- E init: E[v][w] = exp(2*(x[b,v,:]@w_u[w,:] + b_u[w])), wave covers 32 rows ----
#pragma unroll 1
    for (int bb = 0; bb < 2; ++bb) {
        float* E = bb ? EB : EA;
        const int b = bb ? bB : bA;
#pragma unroll 1
        for (int half = 0; half < 2; ++half) {
            float4 wu_r[8];
#pragma unroll
            for (int i = 0; i < 8; ++i)
                wu_r[i] = *(const float4*)&w_u[lane*64 + half*32 + 4*i];
            const float* xb = x + b*16384 + half*32;
#pragma unroll 2
            for (int vi = 0; vi < 32; ++vi) {
                int v = __builtin_amdgcn_readfirstlane(wvi*32 + vi);
                const float4* xr = (const float4*)(xb + v*64);
                float acc = 0.f;
#pragma unroll
                for (int i = 0; i < 8; ++i) {
                    float4 xx = xr[i]; float4 wu = wu_r[i];
                    acc += xx.x*wu.x + xx.y*wu.y + xx.z*wu.z + xx.w*wu.w;
                }
                if (half == 0) E[v*68 + lane] = acc + bu_lane;
                else           E[v*68 + lane] = fexp2(K2LOG2E * (E[v*68 + lane] + acc));
            }
        }
    }
    __syncthreads();

    // ---- P2 thread identity: (xj = tid&255, batch = tid>>8); x_t lives in a register ----
    const int  xj   = tid & 255;
    const int  bsel = tid >> 8;
    const float* xrow = x + (bsel ? bB : bA)*16384 + xj*64;
    const float* Erow = (bsel ? EB : EA) + xj*68;
    const float* ewX  = bsel ? ewB : ewA;
    float*       exfX = bsel ? exfB : exfA;
    unsigned*    xhX  = bsel ? xhB : xhA;
    float xcur = xrow[0];

    for (int t = 0; t < 64; ++t) {
        // ---- P1: wout for both batches (conflict-free interleaved hc reads) ----
        {
            float accA = 0.f, accB = 0.f;
#pragma unroll
            for (int m = 0; m < 4; ++m) {
                float4 w4 = www4[m];
                float4 hA = *(const float4*)&hcA[kg*4 + 32*m];
                float4 hB = *(const float4*)&hcB[kg*4 + 32*m];
                accA += hA.x*w4.x + hA.y*w4.y + hA.z*w4.z + hA.w*w4.w;
                accB += hB.x*w4.x + hB.y*w4.y + hB.z*w4.z + hB.w*w4.w;
            }
#pragma unroll
            for (int off = 8; off <= 32; off <<= 1) {
                accA += __shfl_xor(accA, off, 64);
                accB += __shfl_xor(accB, off, 64);
            }
            if (kg == 0)      ewA[w8] = fexp2(K2LOG2E * (accA + bwr));
            else if (kg == 1) ewB[w8] = fexp2(K2LOG2E * (accB + bwr));
        }
        float xnxt = (t < 63) ? xrow[t + 1] : 0.f;   // prefetch; latency spans B1+P2
        __syncthreads();   // B1

        // ---- P2: full score per thread, 4 independent accumulator chains ----
        {
            float ac0 = 0.f, ac1 = 0.f, ac2 = 0.f, ac3 = 0.f;
#pragma unroll
            for (int q = 0; q < 16; ++q) {
                float4 e4 = *(const float4*)&Erow[4*q];
                float4 c4 = *(const float4*)&ewX[4*q];    // broadcast
                float4 v4 = *(const float4*)&wv2L[4*q];   // broadcast
                ac0 += v4.x * frcp(e4.x*c4.x + 1.f);
                ac1 += v4.y * frcp(e4.y*c4.y + 1.f);
                ac2 += v4.z * frcp(e4.z*c4.z + 1.f);
                ac3 += v4.w * frcp(e4.w*c4.w + 1.f);
            }
            float acc = Sv + ((ac0 + ac1) + (ac2 + ac3));
            float e  = fexp2(KLOG2E * acc);  // |score| <= sum|w_v| ~2.6: no max-subtract
            float ex = e * xcur;
            float s = e;
#pragma unroll
            for (int off = 1; off <= 32; off <<= 1) s += __shfl_xor(s, off, 64);
            if (lane == 0) wsum[wvi] = s;
            exfX[xj] = ex;
            float ex2 = __shfl_xor(ex, 1, 64);
            if (!(lane & 1)) xhX[xj >> 1] = pkrtz_u(ex, ex2);
        }
        xcur = xnxt;
        __syncthreads();   // B2

        // ---- P4: gates partials (jj-structure, 8 x-chains + h-chains) + out_xt ----
        {
            float rA = frcp((wsum[0] + wsum[1]) + (wsum[2] + wsum[3]));
            float rB = frcp((wsum[4] + wsum[5]) + (wsum[6] + wsum[7]));
            out_xt[t*131072 + (bsel ? bB : bA)*256 + xj] = (bsel ? rB : rA) * exfX[xj];

            const int sg = wvi, jg = lane;
            float aA[4] = {0.f, 0.f, 0.f, 0.f};   // x-part, batch A
            float aB[4] = {0.f, 0.f, 0.f, 0.f};   // x-part, batch B
            const uint4* xxA = (const uint4*)xhA + sg*4;   // wave-uniform: broadcast
            const uint4* xxB = (const uint4*)xhB + sg*4;
#pragma unroll
            for (int i = 0; i < 4; ++i) {
                uint4 ua = xxA[i], ub = xxB[i];
                H2U u0, u1, u2, u3, v0, v1, v2, v3;
                u0.u = ua.x; u1.u = ua.y; u2.u = ua.z; u3.u = ua.w;
                v0.u = ub.x; v1.u = ub.y; v2.u = ub.z; v3.u = ub.w;
#pragma unroll
                for (int jj = 0; jj < 4; ++jj) {
                    aA[jj] = fdot2(u0.h, wihr2[jj*16 + 4*i + 0], aA[jj]);
                    aA[jj] = fdot2(u1.h, wihr2[jj*16 + 4*i + 1], aA[jj]);
                    aA[jj] = fdot2(u2.h, wihr2[jj*16 + 4*i + 2], aA[jj]);
                    aA[jj] = fdot2(u3.h, wihr2[jj*16 + 4*i + 3], aA[jj]);
                    aB[jj] = fdot2(v0.h, wihr2[jj*16 + 4*i + 0], aB[jj]);
                    aB[jj] = fdot2(v1.h, wihr2[jj*16 + 4*i + 1], aB[jj]);
                    aB[jj] = fdot2(v2.h, wihr2[jj*16 + 4*i + 2], aB[jj]);
                    aB[jj] = fdot2(v3.h, wihr2[jj*16 + 4*i + 3], aB[jj]);
                }
            }
            // h-part fp32: k-slice [sg*8,+8), hc broadcast reads; separate accumulators
            float4 hA0 = *(const float4*)&hcA[sg*8];
            float4 hA1 = *(const float4*)&hcA[sg*8 + 4];
            float4 hB0 = *(const float4*)&hcB[sg*8];
            float4 hB1 = *(const float4*)&hcB[sg*8 + 4];
#pragma unroll
            for (int jj = 0; jj < 4; ++jj) {
                float hhA = (hA0.x*whhr[jj*8+0] + hA0.y*whhr[jj*8+1])
                          + (hA0.z*whhr[jj*8+2] + hA0.w*whhr[jj*8+3])
                          + (hA1.x*whhr[jj*8+4] + hA1.y*whhr[jj*8+5])
                          + (hA1.z*whhr[jj*8+6] + hA1.w*whhr[jj*8+7]);
                float hhB = (hB0.x*whhr[jj*8+0] + hB0.y*whhr[jj*8+1])
                          + (hB0.z*whhr[jj*8+2] + hB0.w*whhr[jj*8+3])
                          + (hB1.x*whhr[jj*8+4] + hB1.y*whhr[jj*8+5])
                          + (hB1.z*whhr[jj*8+6] + hB1.w*whhr[jj*8+7]);
                psA[sg*256 + jg + 64*jj] = rA*aA[jj] + hhA;
                psB[sg*256 + jg + 64*jj] = rB*aB[jj] + hhB;
            }
        }
        __syncthreads();   // B4

        // ---- P5: LSTM cell (wave0 = A, wave1 = B), tree partial sums ----
        if (wvi < 2) {
            float* ps = wvi ? psB : psA;
            float* hc = wvi ? hcB : hcA;
            float* oh = out_h + t*32768 + (wvi ? bB : bA)*64;
            const int k = lane;
            float gi = biasL[k] +
                (((ps[0*256 + k] + ps[1*256 + k]) + (ps[2*256 + k] + ps[3*256 + k])) +
                 ((ps[4*256 + k] + ps[5*256 + k]) + (ps[6*256 + k] + ps[7*256 + k])));
            float gf = biasL[64 + k] +
                (((ps[0*256 + 64 + k] + ps[1*256 + 64 + k]) + (ps[2*256 + 64 + k] + ps[3*256 + 64 + k])) +
                 ((ps[4*256 + 64 + k] + ps[5*256 + 64 + k]) + (ps[6*256 + 64 + k] + ps[7*256 + 64 + k])));
            float gg = biasL[128 + k] +
                (((ps[0*256 + 128 + k] + ps[1*256 + 128 + k]) + (ps[2*256 + 128 + k] + ps[3*256 + 128 + k])) +
                 ((ps[4*256 + 128 + k] + ps[5*256 + 128 + k]) + (ps[6*256 + 128 + k] + ps[7*256 + 128 + k])));
            float go = biasL[192 + k] +
                (((ps[0*256 + 192 + k] + ps[1*256 + 192 + k]) + (ps[2*256 + 192 + k] + ps[3*256 + 192 + k])) +
                 ((ps[4*256 + 192 + k] + ps[5*256 + 192 + k]) + (ps[6*256 + 192 + k] + ps[7*256 + 192 + k])));
            gi = fsigmoid(gi); gf = fsigmoid(gf);
            gg = ftanh(gg);    go = fsigmoid(go);
            float cn = gf * hc[64 + k] + gi * gg;
            float hn = go * ftanh(cn);
            hc[k] = hn; hc[64 + k] = cn;
            oh[k] = hn;
        }
        __syncthreads();   // B5
    }
}

extern "C" void kernel_launch(void* const* d_in, const int* in_sizes, int n_in,
                              void* d_out, int out_size, void* d_ws, size_t ws_size,
                              hipStream_t stream) {
    const float* x    = (const float*)d_in[0];
    const float* w_ih = (const float*)d_in[1];
    const float* w_hh = (const float*)d_in[2];
    const float* b_ih = (const float*)d_in[3];
    const float* b_hh = (const float*)d_in[4];
    const float* w_v  = (const float*)d_in[5];
    const float* w_w  = (const float*)d_in[6];
    const float* b_w  = (const float*)d_in[7];
    const float* w_u  = (const float*)d_in[8];
    const float* b_u  = (const float*)d_in[9];

    float* out_xt = (float*)d_out;
    float* out_h  = out_xt + 64*512*256;

    const size_t shbytes = (size_t)L_TOT * sizeof(float);  // 161568 B
    (void)hipFuncSetAttribute((const void*)enc_kernel,
                        hipFuncAttributeMaxDynamicSharedMemorySize, (int)shbytes);
    enc_kernel<<<dim3(256), dim3(512), shbytes, stream>>>(
        x, w_ih, w_hh, b_ih, b_hh, w_v, w_w, b_w, w_u, b_u, out_xt, out_h);
}

// Round 12
// 281.599 us; speedup vs baseline: 1.7069x; 1.1155x over previous
//
#include <hip/hip_runtime.h>

// B=512, V=256, W=64, H=64. Outputs: x_tilde_seq (64,512,256) fp32, h_seq (64,512,64) fp32.
// One block = TWO batches (bA, bA+256); 256 blocks x 512 thr, 1 block/CU, 8 waves.
// R6 (306us) structure: P1|B1|P2|B2|P3|B3|P4|B4|P5|B5 — with P4 moved to the MATRIX pipe:
// gates = [2x256]·w_ih^T as mfma_f32_16x16x32_f16, M=2(+14 zero rows), per wave 2 N-tiles
// x (8 K-steps w_ih + 2 K-steps w_hh). B-frags (weights) persistent in regs (64+16),
// A-frags read from fp16-packed LDS (xh = r*e*x from P3; hch = h packed in P5).
// D layout (m89-verified): col = lane&15 (gate row), row = (lane>>4)*4+reg (batch).

#define KLOG2E  1.4426950408889634f   // log2(e)
#define K2LOG2E 2.8853900817779268f   // 2*log2(e)

typedef _Float16 h2    __attribute__((ext_vector_type(2)));
typedef __fp16   f16x8 __attribute__((ext_vector_type(8)));
typedef float    f32x4 __attribute__((ext_vector_type(4)));
union H2U { h2 h; unsigned u; };

__device__ __forceinline__ float frcp(float x)  { return __builtin_amdgcn_rcpf(x); }
__device__ __forceinline__ float fexp2(float x) { return __builtin_amdgcn_exp2f(x); }
__device__ __forceinline__ float fsigmoid(float x) { return frcp(1.f + fexp2(-KLOG2E * x)); }
__device__ __forceinline__ float ftanh(float x) { return 1.f - 2.f * frcp(fexp2(K2LOG2E * x) + 1.f); }

__device__ __forceinline__ unsigned pkrtz_u(float a, float b) {
    H2U r; r.h = __builtin_bit_cast(h2, __builtin_amdgcn_cvt_pkrtz(a, b)); return r.u;
}

// LDS layout (float slots)
#define L_EA   0                    // E_A [256][68] fp32 = exp(2*(u_out+b_u))
#define L_EB   17408                // E_B [256][68]
#define L_PSA  34816                // [512]: P2 e(0..255)/ex(256..511); P4 gates(0..255)
#define L_PSB  35328                // [512]
#define L_XTA  35840                // x_tilde fp32 A [256]
#define L_XTB  36096
#define L_XHA  36352                // x_tilde packed h2 A [128 u32]
#define L_XHB  36480
#define L_EWA  36608                // e_w A [64]
#define L_EWB  36672
#define L_HCA  36736                // h||c fp32 A [128]
#define L_HCB  36864
#define L_HHA  36992                // h packed h2 A [32 u32]
#define L_HHB  37024
#define L_BI   37056                // bias b_ih+b_hh [256]
#define L_WV   37312                // -2*w_v [64]
#define L_TOT  37376                // 149504 bytes <= 160K (1 block/CU)

__global__ __launch_bounds__(512, 2) void enc_kernel(
    const float* __restrict__ x,     // (512,256,64)
    const float* __restrict__ w_ih,  // (256,256)
    const float* __restrict__ w_hh,  // (256,64)
    const float* __restrict__ b_ih,  // (256)
    const float* __restrict__ b_hh,  // (256)
    const float* __restrict__ w_v,   // (64)
    const float* __restrict__ w_w,   // (64,128)
    const float* __restrict__ b_w,   // (64)
    const float* __restrict__ w_u,   // (64,64)
    const float* __restrict__ b_u,   // (64)
    float* __restrict__ out_xt,      // (64,512,256)
    float* __restrict__ out_h)       // (64,512,64)
{
    extern __shared__ float lds[];
    float*    EA   = lds + L_EA;    float*    EB   = lds + L_EB;
    float*    psA  = lds + L_PSA;   float*    psB  = lds + L_PSB;
    float*    xtA  = lds + L_XTA;   float*    xtB  = lds + L_XTB;
    unsigned* xhA  = (unsigned*)(lds + L_XHA);
    unsigned* xhB  = (unsigned*)(lds + L_XHB);
    float*    ewA  = lds + L_EWA;   float*    ewB  = lds + L_EWB;
    float*    hcA  = lds + L_HCA;   float*    hcB  = lds + L_HCB;
    unsigned* hhA  = (unsigned*)(lds + L_HHA);
    unsigned* hhB  = (unsigned*)(lds + L_HHB);
    float*    biasL= lds + L_BI;
    float*    wv2L = lds + L_WV;

    const int tid  = threadIdx.x;
    const int lane = tid & 63;
    const int wvi  = tid >> 6;            // wave 0..7
    const int bA   = blockIdx.x;
    const int bB   = blockIdx.x + 256;

    // ---- persistent MFMA B-fragments: wave wvi owns gate rows [wvi*32,+32) ----
    // B[k][col]: col = lane&15 (+16 for tile1), k = kk*32 + (lane>>4)*8 + i
    f16x8 wbx0[8], wbx1[8], wbh0[2], wbh1[2];
    {
        const int col0 = wvi*32 + (lane & 15);
        const int col1 = col0 + 16;
        const int kofs = (lane >> 4) * 8;
#pragma unroll
        for (int kk = 0; kk < 8; ++kk) {
            const float* s0 = w_ih + col0*256 + kk*32 + kofs;
            const float* s1 = w_ih + col1*256 + kk*32 + kofs;
            f16x8 a, b;
#pragma unroll
            for (int i = 0; i < 8; ++i) { a[i] = (__fp16)s0[i]; b[i] = (__fp16)s1[i]; }
            wbx0[kk] = a; wbx1[kk] = b;
        }
#pragma unroll
        for (int kk = 0; kk < 2; ++kk) {
            const float* s0 = w_hh + col0*64 + kk*32 + kofs;
            const float* s1 = w_hh + col1*64 + kk*32 + kofs;
            f16x8 a, b;
#pragma unroll
            for (int i = 0; i < 8; ++i) { a[i] = (__fp16)s0[i]; b[i] = (__fp16)s1[i]; }
            wbh0[kk] = a; wbh1[kk] = b;
        }
    }
    // wout: thread (w8 = wvi*8+(lane&7), kg = lane>>3) covers k = kg*4 + 32m (m=0..3)
    const int w8 = wvi*8 + (lane & 7);
    const int kg = lane >> 3;
    float4 www4[4];
#pragma unroll
    for (int m = 0; m < 4; ++m)
        www4[m] = *(const float4*)&w_w[w8*128 + kg*4 + 32*m];
    const float bwr = b_w[w8];
    float Sv = 0.f;
#pragma unroll
    for (int wi = 0; wi < 64; ++wi) Sv += w_v[wi];   // uniform scalar loads
    const float bu_lane = b_u[lane];

    // ---- one-time LDS fills ----
    if (tid < 256) biasL[tid] = b_ih[tid] + b_hh[tid];
    if (tid < 64) wv2L[tid] = -2.f * w_v[tid];
    if (tid < 128) { hcA[tid] = 0.f; hcB[tid] = 0.f; }
    if (tid < 32)  { hhA[tid] = 0u; hhB[tid] = 0u; }

    // ---- E init: E[v][w] = exp(2*(x[b,v,:]@w_u[w,:] + b_u[w])), wave covers 32 rows ----
#pragma unroll 1
    for (int bb = 0; bb < 2; ++bb) {
        float* E = bb ? EB : EA;
        const int b = bb ? bB : bA;
#pragma unroll 1
        for (int half = 0; half < 2; ++half) {
            float4 wu_r[8];
#pragma unroll
            for (int i = 0; i < 8; ++i)
                wu_r[i] = *(const float4*)&w_u[lane*64 + half*32 + 4*i];
            const float* xb = x + b*16384 + half*32;
#pragma unroll 2
            for (int vi = 0; vi < 32; ++vi) {
                int v = __builtin_amdgcn_readfirstlane(wvi*32 + vi);
                const float4* xr = (const float4*)(xb + v*64);
                float acc = 0.f;
#pragma unroll
                for (int i = 0; i < 8; ++i) {
                    float4 xx = xr[i]; float4 wu = wu_r[i];
                    acc += xx.x*wu.x + xx.y*wu.y + xx.z*wu.z + xx.w*wu.w;
                }
                if (half == 0) E[v*68 + lane] = acc + bu_lane;
                else           E[v*68 + lane] = fexp2(K2LOG2E * (E[v*68 + lane] + acc));
            }
        }
    }
    __syncthreads();

    // ---- P2 identity: (xj = tid&255, batch = tid>>8); x_t in a register ----
    const int  xj   = tid & 255;
    const int  bsel = tid >> 8;
    const float* xrow = x + (bsel ? bB : bA)*16384 + xj*64;
    const float* Erow = (bsel ? EB : EA) + xj*68;
    const float* ewX  = bsel ? ewB : ewA;
    float*       psX  = bsel ? psB : psA;
    float xcur = xrow[0];

    for (int t = 0; t < 64; ++t) {
        // ---- P1: wout for both batches (conflict-free interleaved hc reads) ----
        {
            float accA = 0.f, accB = 0.f;
#pragma unroll
            for (int m = 0; m < 4; ++m) {
                float4 w4 = www4[m];
                float4 hA = *(const float4*)&hcA[kg*4 + 32*m];
                float4 hB = *(const float4*)&hcB[kg*4 + 32*m];
                accA += hA.x*w4.x + hA.y*w4.y + hA.z*w4.z + hA.w*w4.w;
                accB += hB.x*w4.x + hB.y*w4.y + hB.z*w4.z + hB.w*w4.w;
            }
#pragma unroll
            for (int off = 8; off <= 32; off <<= 1) {
                accA += __shfl_xor(accA, off, 64);
                accB += __shfl_xor(accB, off, 64);
            }
            if (kg == 0)      ewA[w8] = fexp2(K2LOG2E * (accA + bwr));
            else if (kg == 1) ewB[w8] = fexp2(K2LOG2E * (accB + bwr));
        }
        float xnxt = (t < 63) ? xrow[t + 1] : 0.f;   // prefetch; latency spans B1+P2
        __syncthreads();   // B1

        // ---- P2: full score per thread, 4 independent accumulator chains ----
        {
            float ac0 = 0.f, ac1 = 0.f, ac2 = 0.f, ac3 = 0.f;
#pragma unroll
            for (int q = 0; q < 16; ++q) {
                float4 e4 = *(const float4*)&Erow[4*q];
                float4 c4 = *(const float4*)&ewX[4*q];    // broadcast
                float4 v4 = *(const float4*)&wv2L[4*q];   // broadcast
                ac0 += v4.x * frcp(e4.x*c4.x + 1.f);
                ac1 += v4.y * frcp(e4.y*c4.y + 1.f);
                ac2 += v4.z * frcp(e4.z*c4.z + 1.f);
                ac3 += v4.w * frcp(e4.w*c4.w + 1.f);
            }
            float acc = Sv + ((ac0 + ac1) + (ac2 + ac3));
            float e  = fexp2(KLOG2E * acc);  // |score| <= sum|w_v| ~2.6: no max-subtract
            psX[xj]       = e;
            psX[256 + xj] = e * xcur;
        }
        xcur = xnxt;
        __syncthreads();   // B2

        // ---- P3: softmax + x_tilde (wave0 = A, wave1 = B); writes xt fp32 + xh fp16 ----
        if (wvi < 2) {
            float*    ps = wvi ? psB : psA;
            float*    xt = wvi ? xtB : xtA;
            unsigned* xh = wvi ? xhB : xhA;
            float4 ev = *(const float4*)&ps[4*lane];
            float4 ex = *(const float4*)&ps[256 + 4*lane];
            float sum = (ev.x + ev.y) + (ev.z + ev.w);
#pragma unroll
            for (int off = 1; off <= 32; off <<= 1) sum += __shfl_xor(sum, off, 64);
            float r = frcp(sum);
            float4 xo;
            xo.x = ex.x*r; xo.y = ex.y*r; xo.z = ex.z*r; xo.w = ex.w*r;
            *(float4*)&xt[4*lane] = xo;
            xh[2*lane]     = pkrtz_u(xo.x, xo.y);
            xh[2*lane + 1] = pkrtz_u(xo.z, xo.w);
        }
        __syncthreads();   // B3

        // ---- P4: out_xt store + gates via MFMA (matrix pipe) ----
        {
            float xtv = bsel ? xtB[xj] : xtA[xj];
            out_xt[t*131072 + (bsel ? bB : bA)*256 + xj] = xtv;

            const int row = lane & 15;              // M-row: 0=A, 1=B, 2-15 zero
            const int q4  = (lane >> 4) * 4;        // u32 offset of this lane's k-group
            f32x4 ax0 = {0.f,0.f,0.f,0.f}, ax1 = {0.f,0.f,0.f,0.f};
            f32x4 ah0 = {0.f,0.f,0.f,0.f}, ah1 = {0.f,0.f,0.f,0.f};
            const unsigned* xsrc = (row == 1) ? xhB : xhA;
#pragma unroll
            for (int kk = 0; kk < 8; ++kk) {
                f16x8 a = {};
                if (row < 2)
                    a = __builtin_bit_cast(f16x8, *(const uint4*)(xsrc + kk*16 + q4));
                ax0 = __builtin_amdgcn_mfma_f32_16x16x32_f16(a, wbx0[kk], ax0, 0, 0, 0);
                ax1 = __builtin_amdgcn_mfma_f32_16x16x32_f16(a, wbx1[kk], ax1, 0, 0, 0);
            }
            const unsigned* hsrc = (row == 1) ? hhB : hhA;
#pragma unroll
            for (int kk = 0; kk < 2; ++kk) {
                f16x8 a = {};
                if (row < 2)
                    a = __builtin_bit_cast(f16x8, *(const uint4*)(hsrc + kk*16 + q4));
                ah0 = __builtin_amdgcn_mfma_f32_16x16x32_f16(a, wbh0[kk], ah0, 0, 0, 0);
                ah1 = __builtin_amdgcn_mfma_f32_16x16x32_f16(a, wbh1[kk], ah1, 0, 0, 0);
            }
            // D: col = lane&15 (gate row j), row = batch in reg 0 (A) / reg 1 (B)
            if (lane < 16) {
                const int j0 = wvi*32 + lane, j1 = j0 + 16;
                psA[j0] = ax0[0] + ah0[0];
                psA[j1] = ax1[0] + ah1[0];
                psB[j0] = ax0[1] + ah0[1];
                psB[j1] = ax1[1] + ah1[1];
            }
        }
        __syncthreads();   // B4

        // ---- P5: LSTM cell (wave0 = A, wave1 = B); gates already reduced ----
        if (wvi < 2) {
            float*    ps = wvi ? psB : psA;
            float*    hc = wvi ? hcB : hcA;
            unsigned* hh = wvi ? hhB : hhA;
            float*    oh = out_h + t*32768 + (wvi ? bB : bA)*64;
            const int k = lane;
            float gi = fsigmoid(biasL[k      ] + ps[k      ]);
            float gf = fsigmoid(biasL[64  + k] + ps[64  + k]);
            float gg = ftanh   (biasL[128 + k] + ps[128 + k]);
            float go = fsigmoid(biasL[192 + k] + ps[192 + k]);
            float cn = gf * hc[64 + k] + gi * gg;
            float hn = go * ftanh(cn);
            hc[k] = hn; hc[64 + k] = cn;
            float hp = __shfl_xor(hn, 1, 64);
            if (!(lane & 1)) hh[k >> 1] = pkrtz_u(hn, hp);
            oh[k] = hn;
        }
        __syncthreads();   // B5
    }
}

extern "C" void kernel_launch(void* const* d_in, const int* in_sizes, int n_in,
                              void* d_out, int out_size, void* d_ws, size_t ws_size,
                              hipStream_t stream) {
    const float* x    = (const float*)d_in[0];
    const float* w_ih = (const float*)d_in[1];
    const float* w_hh = (const float*)d_in[2];
    const float* b_ih = (const float*)d_in[3];
    const float* b_hh = (const float*)d_in[4];
    const float* w_v  = (const float*)d_in[5];
    const float* w_w  = (const float*)d_in[6];
    const float* b_w  = (const float*)d_in[7];
    const float* w_u  = (const float*)d_in[8];
    const float* b_u  = (const float*)d_in[9];

    float* out_xt = (float*)d_out;
    float* out_h  = out_xt + 64*512*256;

    const size_t shbytes = (size_t)L_TOT * sizeof(float);  // 149504 B
    (void)hipFuncSetAttribute((const void*)enc_kernel,
                        hipFuncAttributeMaxDynamicSharedMemorySize, (int)shbytes);
    enc_kernel<<<dim3(256), dim3(512), shbytes, stream>>>(
        x, w_ih, w_hh, b_ih, b_hh, w_v, w_w, b_w, w_u, b_u, out_xt, out_h);
}